// Round 15
// baseline (940.190 us; speedup 1.0000x reference)
//
#include <hip/hip_runtime.h>
#include <stdint.h>

#define NN 100000
#define NE 1600000
#define NG 512
#define NB_SCAN ((NN + 1023) / 1024)
#define BSH 8                          // 256 nodes per bucket
#define NBUK ((NN + 255) >> 8)         // 391 buckets
#define BCAP 5120                      // slab capacity per bucket
#define P1CH 4096                      // edges per phase-1 block
#define NP1 ((NE + P1CH - 1) / P1CH)   // 391

typedef __attribute__((ext_vector_type(2))) float f32x2;
typedef __attribute__((ext_vector_type(2))) unsigned short u16x2;
typedef __attribute__((ext_vector_type(4))) unsigned short u16x4;
typedef __attribute__((ext_vector_type(4))) unsigned int u32x4;
typedef __attribute__((ext_vector_type(4))) int i32x4;
typedef __attribute__((ext_vector_type(8))) short bf16x8;
typedef __attribute__((ext_vector_type(4))) float f32x4;
typedef unsigned long long u64;

__device__ __forceinline__ float bf2f(unsigned short u) {
  union { unsigned int i; float f; } v; v.i = ((unsigned int)u) << 16; return v.f;
}
__device__ __forceinline__ unsigned short f2bf(float f) {
  union { float f; unsigned int i; } v; v.f = f;
  unsigned int x = v.i;
  return (unsigned short)((x + 0x7fffu + ((x >> 16) & 1u)) >> 16);
}

// ================= bucketed CSR build =================
__global__ __launch_bounds__(256) void p1_kernel(const int* __restrict__ src,
                                                 const int* __restrict__ dst,
                                                 int* __restrict__ bcur,
                                                 u64* __restrict__ pairs) {
  __shared__ u64 buf[P1CH];
  __shared__ int cnt[NBUK], off[NBUK], place[NBUK], gbase[NBUK];
  int tid = threadIdx.x;
  int e0 = blockIdx.x * P1CH;
  int ecnt = min(P1CH, NE - e0);
  for (int i = tid; i < NBUK; i += 256) cnt[i] = 0;
  __syncthreads();
  int ls[16], ld[16];
#pragma unroll
  for (int k = 0; k < 16; ++k) {
    int i = tid + k * 256;
    if (i < ecnt) {
      ls[k] = src[e0 + i];
      ld[k] = dst[e0 + i];
      atomicAdd(&cnt[ld[k] >> BSH], 1);
    }
  }
  __syncthreads();
  if (tid < 64) {
    int base = tid * 7;
    int loc[7];
    int s = 0;
#pragma unroll
    for (int k = 0; k < 7; ++k) {
      int idx = base + k;
      int v = (idx < NBUK) ? cnt[idx] : 0;
      loc[k] = s; s += v;
    }
    int incl = s;
    for (int o = 1; o < 64; o <<= 1) {
      int t = __shfl_up(incl, o, 64);
      if (tid >= o) incl += t;
    }
    int ex = incl - s;
#pragma unroll
    for (int k = 0; k < 7; ++k) {
      int idx = base + k;
      if (idx < NBUK) { off[idx] = ex + loc[k]; place[idx] = ex + loc[k]; }
    }
  }
  __syncthreads();
  for (int b = tid; b < NBUK; b += 256)
    if (cnt[b] > 0) gbase[b] = atomicAdd(&bcur[b], cnt[b]);
  __syncthreads();
#pragma unroll
  for (int k = 0; k < 16; ++k) {
    int i = tid + k * 256;
    if (i < ecnt) {
      int b = ld[k] >> BSH;
      int p = atomicAdd(&place[b], 1);
      buf[p] = ((u64)(unsigned)ld[k] << 32) | (unsigned)ls[k];
    }
  }
  __syncthreads();
  for (int i = tid; i < ecnt; i += 256) {
    u64 pr = buf[i];
    int b = (int)(pr >> 32) >> BSH;
    int idx = gbase[b] + (i - off[b]);
    pairs[(size_t)b * BCAP + idx] = pr;
  }
}

__global__ __launch_bounds__(256) void bcount_kernel(const u64* __restrict__ pairs,
                                                     const int* __restrict__ bcur,
                                                     int* __restrict__ ncnt) {
  int b = blockIdx.x, tid = threadIdx.x;
  __shared__ int cnt[256];
  cnt[tid] = 0;
  __syncthreads();
  int n = bcur[b];
  const u64* pp = pairs + (size_t)b * BCAP;
  for (int i = tid; i < n; i += 256) {
    int d = (int)(pp[i] >> 32);
    atomicAdd(&cnt[d & 255], 1);
  }
  __syncthreads();
  int node = (b << BSH) + tid;
  if (node < NN) ncnt[node] = cnt[tid];
}

__global__ __launch_bounds__(256) void p2_kernel(const u64* __restrict__ pairs,
                                                 const int* __restrict__ bcur,
                                                 const int* __restrict__ rowptr,
                                                 int* __restrict__ esrc) {
  int b = blockIdx.x, tid = threadIdx.x;
  __shared__ int cur[256];
  int node = (b << BSH) + tid;
  cur[tid] = (node < NN) ? rowptr[node] : 0;
  __syncthreads();
  int n = bcur[b];
  const u64* pp = pairs + (size_t)b * BCAP;
  for (int i = tid; i < n; i += 256) {
    u64 pr = pp[i];
    int s = (int)(pr & 0xffffffffu);
    int d = (int)(pr >> 32);
    int p = atomicAdd(&cur[d & 255], 1);
    esrc[p] = s;
  }
}

__global__ __launch_bounds__(256) void bsum_kernel(const int* __restrict__ counts,
                                                   int* __restrict__ bsums) {
  __shared__ int red[256];
  int b = blockIdx.x, tid = threadIdx.x;
  int s = 0;
#pragma unroll
  for (int k = 0; k < 4; ++k) {
    int i = b * 1024 + k * 256 + tid;
    if (i < NN) s += counts[i];
  }
  red[tid] = s;
  __syncthreads();
  for (int off = 128; off > 0; off >>= 1) {
    if (tid < off) red[tid] += red[tid + off];
    __syncthreads();
  }
  if (tid == 0) bsums[b] = red[0];
}

__global__ __launch_bounds__(128) void bscan_kernel(const int* __restrict__ bsums,
                                                    int* __restrict__ boff,
                                                    int* __restrict__ rowptr) {
  __shared__ int buf[128];
  int tid = threadIdx.x;
  int v = (tid < NB_SCAN) ? bsums[tid] : 0;
  buf[tid] = v;
  __syncthreads();
  int incl = v;
  for (int off = 1; off < 128; off <<= 1) {
    int add = (tid >= off) ? buf[tid - off] : 0;
    __syncthreads();
    incl += add;
    buf[tid] = incl;
    __syncthreads();
  }
  if (tid < NB_SCAN) boff[tid] = incl - v;
  if (tid == NB_SCAN - 1) rowptr[NN] = incl;
}

__global__ __launch_bounds__(256) void scan_apply_kernel(const int* __restrict__ counts,
                                                         const int* __restrict__ boff,
                                                         int* __restrict__ rowptr) {
  __shared__ int tsum[256];
  int b = blockIdx.x, tid = threadIdx.x;
  int base = b * 1024 + tid * 4;
  int c[4];
  if (base + 3 < NN) {
    i32x4 cv = *(const i32x4*)(counts + base);
    c[0] = cv[0]; c[1] = cv[1]; c[2] = cv[2]; c[3] = cv[3];
  } else {
#pragma unroll
    for (int k = 0; k < 4; ++k) c[k] = (base + k < NN) ? counts[base + k] : 0;
  }
  int s = c[0] + c[1] + c[2] + c[3];
  tsum[tid] = s;
  __syncthreads();
  int incl = s;
  for (int off = 1; off < 256; off <<= 1) {
    int add = (tid >= off) ? tsum[tid - off] : 0;
    __syncthreads();
    incl += add;
    tsum[tid] = incl;
    __syncthreads();
  }
  int ex = boff[b] + incl - s;
#pragma unroll
  for (int k = 0; k < 4; ++k) {
    int i = base + k;
    if (i < NN) rowptr[i] = ex;
    ex += c[k];
  }
}

// ---------------- conversions ----------------
__global__ __launch_bounds__(256) void convx_kernel(const float* __restrict__ x,
                                                    unsigned short* __restrict__ xb) {
  int t = blockIdx.x * 256 + threadIdx.x;
  int i = t * 4;
  if (i < NN * 128) {
    f32x4 v = *(const f32x4*)(x + i);
    u16x4 o;
    o[0] = f2bf(v[0]); o[1] = f2bf(v[1]); o[2] = f2bf(v[2]); o[3] = f2bf(v[3]);
    *(u16x4*)(xb + i) = o;
  }
}

__global__ __launch_bounds__(256) void wconv_kernel(const float* __restrict__ W,
                                                    unsigned short* __restrict__ Wt,
                                                    int K, int ncols) {
  int t = blockIdx.x * 256 + threadIdx.x;
  if (t < K * ncols) {
    int k = t / ncols, n = t % ncols;
    Wt[n * K + k] = f2bf(W[t]);
  }
}

__global__ __launch_bounds__(256) void bnprep_kernel(const float* __restrict__ gamma,
                                                     const float* __restrict__ beta,
                                                     const float* __restrict__ mean,
                                                     const float* __restrict__ var,
                                                     float* __restrict__ scale,
                                                     float* __restrict__ shift) {
  int t = blockIdx.x * 256 + threadIdx.x;
  if (t < 4 * 256) {
    float s = gamma[t] * rsqrtf(var[t] + 1e-5f);
    scale[t] = s;
    shift[t] = beta[t] - mean[t] * s;
  }
}

// ---------------- aggregation (R13-proven) ----------------
__device__ __forceinline__ void deq4(int w, float s, float& a0, float& a1, float& a2, float& a3) {
  a0 += s * (float)((w << 24) >> 24);
  a1 += s * (float)((w << 16) >> 24);
  a2 += s * (float)((w << 8) >> 24);
  a3 += s * (float)(w >> 24);
}

__global__ __launch_bounds__(256, 8) void agg256_kernel(const signed char* __restrict__ hq,
                                                        const float* __restrict__ hs,
                                                        const int* __restrict__ rowptr,
                                                        const int* __restrict__ esrc,
                                                        unsigned short* __restrict__ out) {
  int node = blockIdx.x * 4 + (threadIdx.x >> 6);
  int lane = threadIdx.x & 63;
  if (node >= NN) return;
  const int* __restrict__ hv = (const int*)hq;  // 4 int8 per lane
  float a0 = 0.f, a1 = 0.f, a2 = 0.f, a3 = 0.f;
  deq4(hv[(size_t)node * 64 + lane], hs[node], a0, a1, a2, a3);
  int p = rowptr[node];
  const int pe = rowptr[node + 1];
  for (; p + 16 <= pe; p += 16) {
    int idx[16];
#pragma unroll
    for (int j = 0; j < 16; ++j) idx[j] = esrc[p + j];
    int w[16]; float sc[16];
#pragma unroll
    for (int j = 0; j < 16; ++j) { w[j] = hv[(size_t)idx[j] * 64 + lane]; sc[j] = hs[idx[j]]; }
#pragma unroll
    for (int j = 0; j < 16; ++j) deq4(w[j], sc[j], a0, a1, a2, a3);
  }
  for (; p + 4 <= pe; p += 4) {
    int idx[4];
#pragma unroll
    for (int j = 0; j < 4; ++j) idx[j] = esrc[p + j];
    int w[4]; float sc[4];
#pragma unroll
    for (int j = 0; j < 4; ++j) { w[j] = hv[(size_t)idx[j] * 64 + lane]; sc[j] = hs[idx[j]]; }
#pragma unroll
    for (int j = 0; j < 4; ++j) deq4(w[j], sc[j], a0, a1, a2, a3);
  }
  for (; p < pe; ++p) deq4(hv[(size_t)esrc[p] * 64 + lane], hs[esrc[p]], a0, a1, a2, a3);
  u16x4 o; o[0] = f2bf(a0); o[1] = f2bf(a1); o[2] = f2bf(a2); o[3] = f2bf(a3);
  union { u16x4 v; u64 q; } cv; cv.v = o;
  __builtin_nontemporal_store(cv.q, (u64*)out + (size_t)node * 64 + lane);
}

__global__ __launch_bounds__(256, 8) void agg128_kernel(const unsigned short* __restrict__ h,
                                                        const int* __restrict__ rowptr,
                                                        const int* __restrict__ esrc,
                                                        unsigned short* __restrict__ out) {
  int node = blockIdx.x * 4 + (threadIdx.x >> 6);
  int lane = threadIdx.x & 63;
  if (node >= NN) return;
  const u16x2* __restrict__ hv = (const u16x2*)h;
  u16x2 v = hv[(size_t)node * 64 + lane];
  float a0 = bf2f(v[0]), a1 = bf2f(v[1]);
  int p = rowptr[node];
  const int pe = rowptr[node + 1];
  for (; p + 8 <= pe; p += 8) {
    int idx[8];
#pragma unroll
    for (int j = 0; j < 8; ++j) idx[j] = esrc[p + j];
    u16x2 u[8];
#pragma unroll
    for (int j = 0; j < 8; ++j) u[j] = hv[(size_t)idx[j] * 64 + lane];
#pragma unroll
    for (int j = 0; j < 8; ++j) { a0 += bf2f(u[j][0]); a1 += bf2f(u[j][1]); }
  }
  for (; p < pe; ++p) {
    u16x2 u = hv[(size_t)esrc[p] * 64 + lane];
    a0 += bf2f(u[0]); a1 += bf2f(u[1]);
  }
  u16x2 o; o[0] = f2bf(a0); o[1] = f2bf(a1);
  ((u16x2*)out)[(size_t)node * 64 + lane] = o;
}

// -------- fused 2-layer MLP, 32-row tile, 2 waves/block, LDS-packed int8 out --------
// LDS ~17.3KB -> 8 blocks/CU (vs 4 at 64-row). NN % 32 == 0 -> all tiles full.
template <int K>
__global__ __launch_bounds__(128, 4) void mlp_kernel(
    const unsigned short* __restrict__ hin, const unsigned short* __restrict__ W1t,
    const float* __restrict__ b1, const unsigned short* __restrict__ W2t,
    const float* __restrict__ b2, const float* __restrict__ bnscale,
    const float* __restrict__ bnshift, signed char* __restrict__ hq,
    float* __restrict__ hscale, int M) {
  constexpr int AP = K + 8;
  constexpr int SP = 264;
  __shared__ unsigned short buf[32 * 264];   // 16896 B, reused A -> S -> byte-pack
  __shared__ float wmax[2][32];
  __shared__ float rowinv[32];
  int tid = threadIdx.x;                     // 0..127
  int lane = tid & 63, w = tid >> 6;         // w in {0,1}: cols [128w, 128w+128)
  int l16 = lane & 15, lhi = lane >> 4;
  int row0 = blockIdx.x * 32;

  // stage A tile (32 x K)
  constexpr int CH = 32 * K / 8;
  for (int ch = tid; ch < CH; ch += 128) {
    int r = ch / (K / 8);
    int c = (ch % (K / 8)) * 8;
    u32x4 val = {0u, 0u, 0u, 0u};
    if (row0 + r < M) val = *(const u32x4*)(hin + (size_t)(row0 + r) * K + c);
    *(u32x4*)(&buf[r * AP + c]) = val;
  }
  __syncthreads();

  // phase A: acc = A @ W1  (2 row-frags x 8 col-frags per wave)
  f32x4 acc[2][8] = {};
#pragma unroll
  for (int ks = 0; ks < K / 32; ++ks) {
    int kk = ks * 32 + lhi * 8;
    bf16x8 a[2], b[8];
#pragma unroll
    for (int mf = 0; mf < 2; ++mf)
      a[mf] = *(const bf16x8*)(&buf[(16 * mf + l16) * AP + kk]);
#pragma unroll
    for (int nf = 0; nf < 8; ++nf)
      b[nf] = *(const bf16x8*)(W1t + (size_t)(128 * w + 16 * nf + l16) * K + kk);
#pragma unroll
    for (int mf = 0; mf < 2; ++mf)
#pragma unroll
      for (int nf = 0; nf < 8; ++nf)
        acc[mf][nf] = __builtin_amdgcn_mfma_f32_16x16x32_bf16(a[mf], b[nf], acc[mf][nf], 0, 0, 0);
  }
  __syncthreads();  // all waves done reading A

  // S = relu(acc + b1) into buf
#pragma unroll
  for (int nf = 0; nf < 8; ++nf) {
    int col = 128 * w + 16 * nf + l16;
    float bias = b1[col];
#pragma unroll
    for (int mf = 0; mf < 2; ++mf) {
      f32x4 v = acc[mf][nf];
#pragma unroll
      for (int j = 0; j < 4; ++j) {
        float x = v[j] + bias;
        x = fmaxf(x, 0.f);
        buf[(16 * mf + lhi * 4 + j) * SP + col] = f2bf(x);
      }
    }
  }
  __syncthreads();

  // phase B: acc2 = S @ W2
  f32x4 acc2[2][8] = {};
#pragma unroll
  for (int ks = 0; ks < 8; ++ks) {
    int kk = ks * 32 + lhi * 8;
    bf16x8 a[2], b[8];
#pragma unroll
    for (int mf = 0; mf < 2; ++mf)
      a[mf] = *(const bf16x8*)(&buf[(16 * mf + l16) * SP + kk]);
#pragma unroll
    for (int nf = 0; nf < 8; ++nf)
      b[nf] = *(const bf16x8*)(W2t + (size_t)(128 * w + 16 * nf + l16) * 256 + kk);
#pragma unroll
    for (int mf = 0; mf < 2; ++mf)
#pragma unroll
      for (int nf = 0; nf < 8; ++nf)
        acc2[mf][nf] = __builtin_amdgcn_mfma_f32_16x16x32_bf16(a[mf], b[nf], acc2[mf][nf], 0, 0, 0);
  }

  // epilogue: BN+ReLU in regs; per-row max via shuffles + cross-wave LDS
  float pmax[2][4];
#pragma unroll
  for (int mf = 0; mf < 2; ++mf)
#pragma unroll
    for (int j = 0; j < 4; ++j) pmax[mf][j] = 0.f;
#pragma unroll
  for (int nf = 0; nf < 8; ++nf) {
    int col = 128 * w + 16 * nf + l16;
    float bias = b2[col], sc = bnscale[col], sh = bnshift[col];
#pragma unroll
    for (int mf = 0; mf < 2; ++mf) {
#pragma unroll
      for (int j = 0; j < 4; ++j) {
        float x = acc2[mf][nf][j] + bias;
        x = x * sc + sh;
        x = fmaxf(x, 0.f);
        acc2[mf][nf][j] = x;
        pmax[mf][j] = fmaxf(pmax[mf][j], x);
      }
    }
  }
#pragma unroll
  for (int mf = 0; mf < 2; ++mf) {
#pragma unroll
    for (int j = 0; j < 4; ++j) {
      float m = pmax[mf][j];
      m = fmaxf(m, __shfl_xor(m, 1, 16));
      m = fmaxf(m, __shfl_xor(m, 2, 16));
      m = fmaxf(m, __shfl_xor(m, 4, 16));
      m = fmaxf(m, __shfl_xor(m, 8, 16));
      pmax[mf][j] = m;
    }
  }
  if (l16 == 0) {
#pragma unroll
    for (int mf = 0; mf < 2; ++mf)
#pragma unroll
      for (int j = 0; j < 4; ++j)
        wmax[w][16 * mf + lhi * 4 + j] = pmax[mf][j];
  }
  __syncthreads();  // wmax ready; also all S reads done -> buf reusable
  if (tid < 32) {
    float m = fmaxf(wmax[0][tid], wmax[1][tid]);
    m = fmaxf(m, 1e-20f);
    rowinv[tid] = 127.f / m;
    int r = row0 + tid;
    if (r < M) hscale[r] = m * (1.f / 127.f);
  }
  __syncthreads();

  // quantize into LDS bytes, then coalesced 16B stores
  char* bufc = (char*)buf;
#pragma unroll
  for (int mf = 0; mf < 2; ++mf) {
#pragma unroll
    for (int j = 0; j < 4; ++j) {
      int lr = 16 * mf + lhi * 4 + j;
      float inv = rowinv[lr];
#pragma unroll
      for (int nf = 0; nf < 8; ++nf) {
        int col = 128 * w + 16 * nf + l16;
        int q = __float2int_rn(acc2[mf][nf][j] * inv);
        bufc[lr * 256 + col] = (char)q;
      }
    }
  }
  __syncthreads();
  for (int ch = tid; ch < 32 * 16; ch += 128) {   // 512 chunks of 16B
    int r = ch >> 4;
    int c = (ch & 15) * 16;
    if (row0 + r < M)
      *(u32x4*)(hq + (size_t)(row0 + r) * 256 + c) = *(const u32x4*)(bufc + r * 256 + c);
  }
}

// ---------------- pooling + classifier (reads int8 table) ----------------
__global__ __launch_bounds__(256) void pool_classify_kernel(
    const signed char* __restrict__ hq, const float* __restrict__ hs,
    const int* __restrict__ batch, const float* __restrict__ Wc,
    const float* __restrict__ bc, float* __restrict__ out) {
  int g = blockIdx.x;
  int tid = threadIdx.x;
  __shared__ int bounds[2];
  if (tid < 2) {
    int target = g + tid;
    int lo = 0, hi = NN;
    while (lo < hi) {
      int mid = (lo + hi) >> 1;
      if (batch[mid] < target) lo = mid + 1; else hi = mid;
    }
    bounds[tid] = lo;
  }
  __syncthreads();
  int s = bounds[0], e = bounds[1];
  float sum = 0.f;
  for (int i = s; i < e; ++i)
    sum += hs[i] * (float)hq[(size_t)i * 256 + tid];
  int cnt = e - s;
  float p = sum / (float)(cnt > 1 ? cnt : 1);
  __shared__ float red[256];
  for (int c = 0; c < 10; ++c) {
    red[tid] = p * Wc[tid * 10 + c];
    __syncthreads();
    for (int off = 128; off > 0; off >>= 1) {
      if (tid < off) red[tid] += red[tid + off];
      __syncthreads();
    }
    if (tid == 0) out[g * 10 + c] = red[0] + bc[c];
    __syncthreads();
  }
}

extern "C" void kernel_launch(void* const* d_in, const int* in_sizes, int n_in,
                              void* d_out, int out_size, void* d_ws, size_t ws_size,
                              hipStream_t stream) {
  const float* x = (const float*)d_in[0];
  const int* src = (const int*)d_in[1];
  const int* dst = (const int*)d_in[2];
  const int* batch = (const int*)d_in[3];
  const float* W1_0 = (const float*)d_in[4];
  const float* b1_0 = (const float*)d_in[5];
  const float* W2_0 = (const float*)d_in[6];
  const float* b2_0 = (const float*)d_in[7];
  const float* W1_r = (const float*)d_in[8];
  const float* b1_r = (const float*)d_in[9];
  const float* W2_r = (const float*)d_in[10];
  const float* b2_r = (const float*)d_in[11];
  const float* bn_gamma = (const float*)d_in[12];
  const float* bn_beta = (const float*)d_in[13];
  const float* bn_mean = (const float*)d_in[14];
  const float* bn_var = (const float*)d_in[15];
  const float* Wc = (const float*)d_in[16];
  const float* bc = (const float*)d_in[17];
  float* out = (float*)d_out;

  char* base = (char*)d_ws;
  size_t off = 0;
  auto take = [&](size_t bytes) {
    size_t cur = off;
    off += (bytes + 255) & ~(size_t)255;
    return cur;
  };
  int* bcur = (int*)(base + take((size_t)NBUK * 4));
  u64* pairs = (u64*)(base + take((size_t)NBUK * BCAP * 8));
  int* ncnt = (int*)(base + take((size_t)NN * 4));
  int* rowptr = (int*)(base + take((size_t)(NN + 1) * 4));
  int* esrc = (int*)(base + take((size_t)NE * 4));
  unsigned short* xb = (unsigned short*)(base + take((size_t)NN * 128 * 2));
  signed char* hq = (signed char*)(base + take((size_t)NN * 256));
  float* hscale = (float*)(base + take((size_t)NN * 4));
  unsigned short* hin = (unsigned short*)(base + take((size_t)NN * 256 * 2));
  unsigned short* W1_0t = (unsigned short*)(base + take(256 * 128 * 2));
  unsigned short* W2_0t = (unsigned short*)(base + take(256 * 256 * 2));
  unsigned short* W1_rt = (unsigned short*)(base + take(3 * 256 * 256 * 2));
  unsigned short* W2_rt = (unsigned short*)(base + take(3 * 256 * 256 * 2));
  float* bnscale = (float*)(base + take(4 * 256 * 4));
  float* bnshift = (float*)(base + take(4 * 256 * 4));
  int* bsums = (int*)(base + take(NB_SCAN * 4));
  int* boff = (int*)(base + take(NB_SCAN * 4));
  (void)ws_size; (void)in_sizes; (void)n_in; (void)out_size;

  // bucketed CSR build
  (void)hipMemsetAsync(bcur, 0, (size_t)NBUK * 4, stream);
  p1_kernel<<<NP1, 256, 0, stream>>>(src, dst, bcur, pairs);
  bcount_kernel<<<NBUK, 256, 0, stream>>>(pairs, bcur, ncnt);
  bsum_kernel<<<NB_SCAN, 256, 0, stream>>>(ncnt, bsums);
  bscan_kernel<<<1, 128, 0, stream>>>(bsums, boff, rowptr);
  scan_apply_kernel<<<NB_SCAN, 256, 0, stream>>>(ncnt, boff, rowptr);
  p2_kernel<<<NBUK, 256, 0, stream>>>(pairs, bcur, rowptr, esrc);

  // conversions
  convx_kernel<<<NN * 128 / 4 / 256, 256, 0, stream>>>(x, xb);
  wconv_kernel<<<128, 256, 0, stream>>>(W1_0, W1_0t, 128, 256);
  wconv_kernel<<<256, 256, 0, stream>>>(W2_0, W2_0t, 256, 256);
  for (int i = 0; i < 3; ++i) {
    wconv_kernel<<<256, 256, 0, stream>>>(W1_r + (size_t)i * 65536, W1_rt + (size_t)i * 65536, 256, 256);
    wconv_kernel<<<256, 256, 0, stream>>>(W2_r + (size_t)i * 65536, W2_rt + (size_t)i * 65536, 256, 256);
  }
  bnprep_kernel<<<4, 256, 0, stream>>>(bn_gamma, bn_beta, bn_mean, bn_var, bnscale, bnshift);

  const int aggGrid = (NN + 3) / 4;
  const int mlpGrid = (NN + 31) / 32;

  // layer 0
  agg128_kernel<<<aggGrid, 256, 0, stream>>>(xb, rowptr, esrc, hin);
  mlp_kernel<128><<<mlpGrid, 128, 0, stream>>>(hin, W1_0t, b1_0, W2_0t, b2_0,
                                               bnscale, bnshift, hq, hscale, NN);
  // layers 1..3
  for (int i = 0; i < 3; ++i) {
    agg256_kernel<<<aggGrid, 256, 0, stream>>>(hq, hscale, rowptr, esrc, hin);
    mlp_kernel<256><<<mlpGrid, 128, 0, stream>>>(
        hin, W1_rt + (size_t)i * 65536, b1_r + (size_t)i * 256,
        W2_rt + (size_t)i * 65536, b2_r + (size_t)i * 256,
        bnscale + (size_t)(i + 1) * 256, bnshift + (size_t)(i + 1) * 256, hq, hscale, NN);
  }

  pool_classify_kernel<<<NG, 256, 0, stream>>>(hq, hscale, batch, Wc, bc, out);
}

// Round 16
// 683.892 us; speedup vs baseline: 1.3748x; 1.3748x over previous
//
#include <hip/hip_runtime.h>
#include <stdint.h>

#define NN 100000
#define NE 1600000
#define NG 512
#define NB_SCAN ((NN + 1023) / 1024)
#define BSH 8                          // 256 nodes per bucket
#define NBUK ((NN + 255) >> 8)         // 391 buckets
#define BCAP 5120                      // slab capacity per bucket
#define P1CH 4096                      // edges per phase-1 block
#define NP1 ((NE + P1CH - 1) / P1CH)   // 391

typedef __attribute__((ext_vector_type(2))) float f32x2;
typedef __attribute__((ext_vector_type(2))) unsigned short u16x2;
typedef __attribute__((ext_vector_type(4))) unsigned short u16x4;
typedef __attribute__((ext_vector_type(4))) unsigned int u32x4;
typedef __attribute__((ext_vector_type(4))) int i32x4;
typedef __attribute__((ext_vector_type(8))) short bf16x8;
typedef __attribute__((ext_vector_type(4))) float f32x4;
typedef unsigned long long u64;

__device__ __forceinline__ float bf2f(unsigned short u) {
  union { unsigned int i; float f; } v; v.i = ((unsigned int)u) << 16; return v.f;
}
__device__ __forceinline__ unsigned short f2bf(float f) {
  union { float f; unsigned int i; } v; v.f = f;
  unsigned int x = v.i;
  return (unsigned short)((x + 0x7fffu + ((x >> 16) & 1u)) >> 16);
}

// ================= bucketed CSR build =================
__global__ __launch_bounds__(256) void p1_kernel(const int* __restrict__ src,
                                                 const int* __restrict__ dst,
                                                 int* __restrict__ bcur,
                                                 u64* __restrict__ pairs) {
  __shared__ u64 buf[P1CH];
  __shared__ int cnt[NBUK], off[NBUK], place[NBUK], gbase[NBUK];
  int tid = threadIdx.x;
  int e0 = blockIdx.x * P1CH;
  int ecnt = min(P1CH, NE - e0);
  for (int i = tid; i < NBUK; i += 256) cnt[i] = 0;
  __syncthreads();
  int ls[16], ld[16];
#pragma unroll
  for (int k = 0; k < 16; ++k) {
    int i = tid + k * 256;
    if (i < ecnt) {
      ls[k] = src[e0 + i];
      ld[k] = dst[e0 + i];
      atomicAdd(&cnt[ld[k] >> BSH], 1);
    }
  }
  __syncthreads();
  if (tid < 64) {
    int base = tid * 7;
    int loc[7];
    int s = 0;
#pragma unroll
    for (int k = 0; k < 7; ++k) {
      int idx = base + k;
      int v = (idx < NBUK) ? cnt[idx] : 0;
      loc[k] = s; s += v;
    }
    int incl = s;
    for (int o = 1; o < 64; o <<= 1) {
      int t = __shfl_up(incl, o, 64);
      if (tid >= o) incl += t;
    }
    int ex = incl - s;
#pragma unroll
    for (int k = 0; k < 7; ++k) {
      int idx = base + k;
      if (idx < NBUK) { off[idx] = ex + loc[k]; place[idx] = ex + loc[k]; }
    }
  }
  __syncthreads();
  for (int b = tid; b < NBUK; b += 256)
    if (cnt[b] > 0) gbase[b] = atomicAdd(&bcur[b], cnt[b]);
  __syncthreads();
#pragma unroll
  for (int k = 0; k < 16; ++k) {
    int i = tid + k * 256;
    if (i < ecnt) {
      int b = ld[k] >> BSH;
      int p = atomicAdd(&place[b], 1);
      buf[p] = ((u64)(unsigned)ld[k] << 32) | (unsigned)ls[k];
    }
  }
  __syncthreads();
  for (int i = tid; i < ecnt; i += 256) {
    u64 pr = buf[i];
    int b = (int)(pr >> 32) >> BSH;
    int idx = gbase[b] + (i - off[b]);
    pairs[(size_t)b * BCAP + idx] = pr;
  }
}

__global__ __launch_bounds__(256) void bcount_kernel(const u64* __restrict__ pairs,
                                                     const int* __restrict__ bcur,
                                                     int* __restrict__ ncnt) {
  int b = blockIdx.x, tid = threadIdx.x;
  __shared__ int cnt[256];
  cnt[tid] = 0;
  __syncthreads();
  int n = bcur[b];
  const u64* pp = pairs + (size_t)b * BCAP;
  for (int i = tid; i < n; i += 256) {
    int d = (int)(pp[i] >> 32);
    atomicAdd(&cnt[d & 255], 1);
  }
  __syncthreads();
  int node = (b << BSH) + tid;
  if (node < NN) ncnt[node] = cnt[tid];
}

__global__ __launch_bounds__(256) void p2_kernel(const u64* __restrict__ pairs,
                                                 const int* __restrict__ bcur,
                                                 const int* __restrict__ rowptr,
                                                 int* __restrict__ esrc) {
  int b = blockIdx.x, tid = threadIdx.x;
  __shared__ int cur[256];
  int node = (b << BSH) + tid;
  cur[tid] = (node < NN) ? rowptr[node] : 0;
  __syncthreads();
  int n = bcur[b];
  const u64* pp = pairs + (size_t)b * BCAP;
  for (int i = tid; i < n; i += 256) {
    u64 pr = pp[i];
    int s = (int)(pr & 0xffffffffu);
    int d = (int)(pr >> 32);
    int p = atomicAdd(&cur[d & 255], 1);
    esrc[p] = s;
  }
}

__global__ __launch_bounds__(256) void bsum_kernel(const int* __restrict__ counts,
                                                   int* __restrict__ bsums) {
  __shared__ int red[256];
  int b = blockIdx.x, tid = threadIdx.x;
  int s = 0;
#pragma unroll
  for (int k = 0; k < 4; ++k) {
    int i = b * 1024 + k * 256 + tid;
    if (i < NN) s += counts[i];
  }
  red[tid] = s;
  __syncthreads();
  for (int off = 128; off > 0; off >>= 1) {
    if (tid < off) red[tid] += red[tid + off];
    __syncthreads();
  }
  if (tid == 0) bsums[b] = red[0];
}

__global__ __launch_bounds__(128) void bscan_kernel(const int* __restrict__ bsums,
                                                    int* __restrict__ boff,
                                                    int* __restrict__ rowptr) {
  __shared__ int buf[128];
  int tid = threadIdx.x;
  int v = (tid < NB_SCAN) ? bsums[tid] : 0;
  buf[tid] = v;
  __syncthreads();
  int incl = v;
  for (int off = 1; off < 128; off <<= 1) {
    int add = (tid >= off) ? buf[tid - off] : 0;
    __syncthreads();
    incl += add;
    buf[tid] = incl;
    __syncthreads();
  }
  if (tid < NB_SCAN) boff[tid] = incl - v;
  if (tid == NB_SCAN - 1) rowptr[NN] = incl;
}

__global__ __launch_bounds__(256) void scan_apply_kernel(const int* __restrict__ counts,
                                                         const int* __restrict__ boff,
                                                         int* __restrict__ rowptr) {
  __shared__ int tsum[256];
  int b = blockIdx.x, tid = threadIdx.x;
  int base = b * 1024 + tid * 4;
  int c[4];
  if (base + 3 < NN) {
    i32x4 cv = *(const i32x4*)(counts + base);
    c[0] = cv[0]; c[1] = cv[1]; c[2] = cv[2]; c[3] = cv[3];
  } else {
#pragma unroll
    for (int k = 0; k < 4; ++k) c[k] = (base + k < NN) ? counts[base + k] : 0;
  }
  int s = c[0] + c[1] + c[2] + c[3];
  tsum[tid] = s;
  __syncthreads();
  int incl = s;
  for (int off = 1; off < 256; off <<= 1) {
    int add = (tid >= off) ? tsum[tid - off] : 0;
    __syncthreads();
    incl += add;
    tsum[tid] = incl;
    __syncthreads();
  }
  int ex = boff[b] + incl - s;
#pragma unroll
  for (int k = 0; k < 4; ++k) {
    int i = base + k;
    if (i < NN) rowptr[i] = ex;
    ex += c[k];
  }
}

// ---------------- conversions ----------------
__global__ __launch_bounds__(256) void convx_kernel(const float* __restrict__ x,
                                                    unsigned short* __restrict__ xb) {
  int t = blockIdx.x * 256 + threadIdx.x;
  int i = t * 4;
  if (i < NN * 128) {
    f32x4 v = *(const f32x4*)(x + i);
    u16x4 o;
    o[0] = f2bf(v[0]); o[1] = f2bf(v[1]); o[2] = f2bf(v[2]); o[3] = f2bf(v[3]);
    *(u16x4*)(xb + i) = o;
  }
}

__global__ __launch_bounds__(256) void wconv_kernel(const float* __restrict__ W,
                                                    unsigned short* __restrict__ Wt,
                                                    int K, int ncols) {
  int t = blockIdx.x * 256 + threadIdx.x;
  if (t < K * ncols) {
    int k = t / ncols, n = t % ncols;
    Wt[n * K + k] = f2bf(W[t]);
  }
}

__global__ __launch_bounds__(256) void bnprep_kernel(const float* __restrict__ gamma,
                                                     const float* __restrict__ beta,
                                                     const float* __restrict__ mean,
                                                     const float* __restrict__ var,
                                                     float* __restrict__ scale,
                                                     float* __restrict__ shift) {
  int t = blockIdx.x * 256 + threadIdx.x;
  if (t < 4 * 256) {
    float s = gamma[t] * rsqrtf(var[t] + 1e-5f);
    scale[t] = s;
    shift[t] = beta[t] - mean[t] * s;
  }
}

// ---------------- aggregation ----------------
__device__ __forceinline__ void deq4(int w, float s, float& a0, float& a1, float& a2, float& a3) {
  a0 += s * (float)((w << 24) >> 24);
  a1 += s * (float)((w << 16) >> 24);
  a2 += s * (float)((w << 8) >> 24);
  a3 += s * (float)(w >> 24);
}

// agg256: int8 table in, int8 (+scale) out — wave-shuffle absmax, no barriers
__global__ __launch_bounds__(256, 8) void agg256_kernel(const signed char* __restrict__ hq,
                                                        const float* __restrict__ hs,
                                                        const int* __restrict__ rowptr,
                                                        const int* __restrict__ esrc,
                                                        signed char* __restrict__ outq,
                                                        float* __restrict__ outs) {
  int node = blockIdx.x * 4 + (threadIdx.x >> 6);
  int lane = threadIdx.x & 63;
  if (node >= NN) return;
  const int* __restrict__ hv = (const int*)hq;  // 4 int8 per lane
  float a0 = 0.f, a1 = 0.f, a2 = 0.f, a3 = 0.f;
  deq4(hv[(size_t)node * 64 + lane], hs[node], a0, a1, a2, a3);
  int p = rowptr[node];
  const int pe = rowptr[node + 1];
  for (; p + 16 <= pe; p += 16) {
    int idx[16];
#pragma unroll
    for (int j = 0; j < 16; ++j) idx[j] = esrc[p + j];
    int w[16]; float sc[16];
#pragma unroll
    for (int j = 0; j < 16; ++j) { w[j] = hv[(size_t)idx[j] * 64 + lane]; sc[j] = hs[idx[j]]; }
#pragma unroll
    for (int j = 0; j < 16; ++j) deq4(w[j], sc[j], a0, a1, a2, a3);
  }
  for (; p + 4 <= pe; p += 4) {
    int idx[4];
#pragma unroll
    for (int j = 0; j < 4; ++j) idx[j] = esrc[p + j];
    int w[4]; float sc[4];
#pragma unroll
    for (int j = 0; j < 4; ++j) { w[j] = hv[(size_t)idx[j] * 64 + lane]; sc[j] = hs[idx[j]]; }
#pragma unroll
    for (int j = 0; j < 4; ++j) deq4(w[j], sc[j], a0, a1, a2, a3);
  }
  for (; p < pe; ++p) deq4(hv[(size_t)esrc[p] * 64 + lane], hs[esrc[p]], a0, a1, a2, a3);
  // per-node absmax via wave butterfly, then int8 quant (1 dword/lane, coalesced)
  float m = fmaxf(fmaxf(fabsf(a0), fabsf(a1)), fmaxf(fabsf(a2), fabsf(a3)));
  for (int o = 1; o < 64; o <<= 1) m = fmaxf(m, __shfl_xor(m, o, 64));
  m = fmaxf(m, 1e-20f);
  float inv = 127.f / m;
  int q0 = __float2int_rn(a0 * inv), q1 = __float2int_rn(a1 * inv);
  int q2 = __float2int_rn(a2 * inv), q3 = __float2int_rn(a3 * inv);
  unsigned int pk = (q0 & 255) | ((q1 & 255) << 8) | ((q2 & 255) << 16) | ((q3 & 255) << 24);
  ((unsigned int*)outq)[(size_t)node * 64 + lane] = pk;
  if (lane == 0) outs[node] = m * (1.f / 127.f);
}

// agg128: bf16 x-table, bf16 out (layer 0; x can be negative, bf16 is proven here)
__global__ __launch_bounds__(256, 8) void agg128_kernel(const unsigned short* __restrict__ h,
                                                        const int* __restrict__ rowptr,
                                                        const int* __restrict__ esrc,
                                                        unsigned short* __restrict__ out) {
  int node = blockIdx.x * 4 + (threadIdx.x >> 6);
  int lane = threadIdx.x & 63;
  if (node >= NN) return;
  const u16x2* __restrict__ hv = (const u16x2*)h;
  u16x2 v = hv[(size_t)node * 64 + lane];
  float a0 = bf2f(v[0]), a1 = bf2f(v[1]);
  int p = rowptr[node];
  const int pe = rowptr[node + 1];
  for (; p + 8 <= pe; p += 8) {
    int idx[8];
#pragma unroll
    for (int j = 0; j < 8; ++j) idx[j] = esrc[p + j];
    u16x2 u[8];
#pragma unroll
    for (int j = 0; j < 8; ++j) u[j] = hv[(size_t)idx[j] * 64 + lane];
#pragma unroll
    for (int j = 0; j < 8; ++j) { a0 += bf2f(u[j][0]); a1 += bf2f(u[j][1]); }
  }
  for (; p < pe; ++p) {
    u16x2 u = hv[(size_t)esrc[p] * 64 + lane];
    a0 += bf2f(u[0]); a1 += bf2f(u[1]);
  }
  u16x2 o; o[0] = f2bf(a0); o[1] = f2bf(a1);
  ((u16x2*)out)[(size_t)node * 64 + lane] = o;
}

// ---- fused 2-layer MLP + BN + ReLU -> int8 out (LDS-packed coalesced stores) ----
// R13 structure: 64-row tile, 4 waves, ONE 34KB LDS buffer (A -> S -> byte-pack).
// K=128: bf16 input (hinb). K=256: int8 input (hinq + hins), decoded during staging.
template <int K>
__global__ __launch_bounds__(256, 4) void mlp_kernel(
    const unsigned short* __restrict__ hinb, const signed char* __restrict__ hinq,
    const float* __restrict__ hins, const unsigned short* __restrict__ W1t,
    const float* __restrict__ b1, const unsigned short* __restrict__ W2t,
    const float* __restrict__ b2, const float* __restrict__ bnscale,
    const float* __restrict__ bnshift, signed char* __restrict__ hq,
    float* __restrict__ hscale, int M) {
  constexpr int AP = K + 8;
  constexpr int SP = 264;
  __shared__ unsigned short buf[64 * 264];   // 33792 B, reused A -> S -> int8 pack
  __shared__ float wmax[4][64];
  __shared__ float rowinv[64];
  int tid = threadIdx.x;
  int lane = tid & 63, w = tid >> 6;
  int l16 = lane & 15, lhi = lane >> 4;
  int row0 = blockIdx.x * 64;

  // stage A tile (64 x K)
  if constexpr (K == 128) {
    constexpr int CH = 64 * K / 8;
    for (int ch = tid; ch < CH; ch += 256) {
      int r = ch / (K / 8);
      int c = (ch % (K / 8)) * 8;
      u32x4 val = {0u, 0u, 0u, 0u};
      if (row0 + r < M) val = *(const u32x4*)(hinb + (size_t)(row0 + r) * K + c);
      *(u32x4*)(&buf[r * AP + c]) = val;
    }
  } else {
    // int8 input: load 8 bytes/chunk, decode to bf16 with per-row scale
    for (int ch = tid; ch < 2048; ch += 256) {
      int r = ch >> 5;
      int c = (ch & 31) * 8;
      int gr = row0 + r;
      unsigned int w0 = 0u, w1 = 0u; float s = 0.f;
      if (gr < M) {
        const unsigned int* p = (const unsigned int*)(hinq + (size_t)gr * 256 + c);
        w0 = p[0]; w1 = p[1];
        s = hins[gr];
      }
      u32x4 outv;
#pragma unroll
      for (int h = 0; h < 2; ++h) {
        unsigned int wv = h ? w1 : w0;
        unsigned short c0 = f2bf(s * (float)((int)(wv << 24) >> 24));
        unsigned short c1 = f2bf(s * (float)((int)(wv << 16) >> 24));
        unsigned short c2 = f2bf(s * (float)((int)(wv << 8) >> 24));
        unsigned short c3 = f2bf(s * (float)((int)wv >> 24));
        outv[2 * h] = (unsigned)c0 | ((unsigned)c1 << 16);
        outv[2 * h + 1] = (unsigned)c2 | ((unsigned)c3 << 16);
      }
      *(u32x4*)(&buf[r * AP + c]) = outv;
    }
  }
  __syncthreads();

  // phase A: acc = A @ W1
  f32x4 acc[4][4] = {};
#pragma unroll
  for (int ks = 0; ks < K / 32; ++ks) {
    int kk = ks * 32 + lhi * 8;
    bf16x8 a[4], b[4];
#pragma unroll
    for (int mf = 0; mf < 4; ++mf)
      a[mf] = *(const bf16x8*)(&buf[(16 * mf + l16) * AP + kk]);
#pragma unroll
    for (int nf = 0; nf < 4; ++nf)
      b[nf] = *(const bf16x8*)(W1t + (size_t)(64 * w + 16 * nf + l16) * K + kk);
#pragma unroll
    for (int mf = 0; mf < 4; ++mf)
#pragma unroll
      for (int nf = 0; nf < 4; ++nf)
        acc[mf][nf] = __builtin_amdgcn_mfma_f32_16x16x32_bf16(a[mf], b[nf], acc[mf][nf], 0, 0, 0);
  }
  __syncthreads();  // all waves done reading A

  // S = relu(acc + b1) into buf
#pragma unroll
  for (int nf = 0; nf < 4; ++nf) {
    int col = 64 * w + 16 * nf + l16;
    float bias = b1[col];
#pragma unroll
    for (int mf = 0; mf < 4; ++mf) {
      f32x4 v = acc[mf][nf];
#pragma unroll
      for (int j = 0; j < 4; ++j) {
        float x = v[j] + bias;
        x = fmaxf(x, 0.f);
        buf[(16 * mf + lhi * 4 + j) * SP + col] = f2bf(x);
      }
    }
  }
  __syncthreads();

  // phase B: acc2 = S @ W2
  f32x4 acc2[4][4] = {};
#pragma unroll
  for (int ks = 0; ks < 8; ++ks) {
    int kk = ks * 32 + lhi * 8;
    bf16x8 a[4], b[4];
#pragma unroll
    for (int mf = 0; mf < 4; ++mf)
      a[mf] = *(const bf16x8*)(&buf[(16 * mf + l16) * SP + kk]);
#pragma unroll
    for (int nf = 0; nf < 4; ++nf)
      b[nf] = *(const bf16x8*)(W2t + (size_t)(64 * w + 16 * nf + l16) * 256 + kk);
#pragma unroll
    for (int mf = 0; mf < 4; ++mf)
#pragma unroll
      for (int nf = 0; nf < 4; ++nf)
        acc2[mf][nf] = __builtin_amdgcn_mfma_f32_16x16x32_bf16(a[mf], b[nf], acc2[mf][nf], 0, 0, 0);
  }

  // epilogue: BN+ReLU in regs; per-row max via shuffles (no atomics)
  float pmax[4][4];
#pragma unroll
  for (int mf = 0; mf < 4; ++mf)
#pragma unroll
    for (int j = 0; j < 4; ++j) pmax[mf][j] = 0.f;
#pragma unroll
  for (int nf = 0; nf < 4; ++nf) {
    int col = 64 * w + 16 * nf + l16;
    float bias = b2[col], sc = bnscale[col], sh = bnshift[col];
#pragma unroll
    for (int mf = 0; mf < 4; ++mf) {
#pragma unroll
      for (int j = 0; j < 4; ++j) {
        float x = acc2[mf][nf][j] + bias;
        x = x * sc + sh;
        x = fmaxf(x, 0.f);
        acc2[mf][nf][j] = x;
        pmax[mf][j] = fmaxf(pmax[mf][j], x);
      }
    }
  }
#pragma unroll
  for (int mf = 0; mf < 4; ++mf) {
#pragma unroll
    for (int j = 0; j < 4; ++j) {
      float m = pmax[mf][j];
      m = fmaxf(m, __shfl_xor(m, 1, 16));
      m = fmaxf(m, __shfl_xor(m, 2, 16));
      m = fmaxf(m, __shfl_xor(m, 4, 16));
      m = fmaxf(m, __shfl_xor(m, 8, 16));
      pmax[mf][j] = m;
    }
  }
  if (l16 == 0) {
#pragma unroll
    for (int mf = 0; mf < 4; ++mf)
#pragma unroll
      for (int j = 0; j < 4; ++j)
        wmax[w][16 * mf + lhi * 4 + j] = pmax[mf][j];
  }
  __syncthreads();  // all waves past GEMM2 -> buf reusable; wmax ready
  if (tid < 64) {
    float m = fmaxf(fmaxf(wmax[0][tid], wmax[1][tid]), fmaxf(wmax[2][tid], wmax[3][tid]));
    m = fmaxf(m, 1e-20f);
    rowinv[tid] = 127.f / m;
    int r = row0 + tid;
    if (r < M) hscale[r] = m * (1.f / 127.f);
  }
  __syncthreads();

  // quantize into LDS bytes, then coalesced 16B copy-out
  char* bufc = (char*)buf;
#pragma unroll
  for (int mf = 0; mf < 4; ++mf) {
#pragma unroll
    for (int j = 0; j < 4; ++j) {
      int lr = 16 * mf + lhi * 4 + j;
      float inv = rowinv[lr];
#pragma unroll
      for (int nf = 0; nf < 4; ++nf) {
        int col = 64 * w + 16 * nf + l16;
        int q = __float2int_rn(acc2[mf][nf][j] * inv);
        bufc[lr * 256 + col] = (char)q;
      }
    }
  }
  __syncthreads();
  for (int ch = tid; ch < 64 * 16; ch += 256) {   // 1024 chunks of 16B
    int r = ch >> 4;
    int c = (ch & 15) * 16;
    if (row0 + r < M)
      *(u32x4*)(hq + (size_t)(row0 + r) * 256 + c) = *(const u32x4*)(bufc + r * 256 + c);
  }
}

// ---------------- pooling + classifier (reads int8 table) ----------------
__global__ __launch_bounds__(256) void pool_classify_kernel(
    const signed char* __restrict__ hq, const float* __restrict__ hs,
    const int* __restrict__ batch, const float* __restrict__ Wc,
    const float* __restrict__ bc, float* __restrict__ out) {
  int g = blockIdx.x;
  int tid = threadIdx.x;
  __shared__ int bounds[2];
  if (tid < 2) {
    int target = g + tid;
    int lo = 0, hi = NN;
    while (lo < hi) {
      int mid = (lo + hi) >> 1;
      if (batch[mid] < target) lo = mid + 1; else hi = mid;
    }
    bounds[tid] = lo;
  }
  __syncthreads();
  int s = bounds[0], e = bounds[1];
  float sum = 0.f;
  for (int i = s; i < e; ++i)
    sum += hs[i] * (float)hq[(size_t)i * 256 + tid];
  int cnt = e - s;
  float p = sum / (float)(cnt > 1 ? cnt : 1);
  __shared__ float red[256];
  for (int c = 0; c < 10; ++c) {
    red[tid] = p * Wc[tid * 10 + c];
    __syncthreads();
    for (int off = 128; off > 0; off >>= 1) {
      if (tid < off) red[tid] += red[tid + off];
      __syncthreads();
    }
    if (tid == 0) out[g * 10 + c] = red[0] + bc[c];
    __syncthreads();
  }
}

extern "C" void kernel_launch(void* const* d_in, const int* in_sizes, int n_in,
                              void* d_out, int out_size, void* d_ws, size_t ws_size,
                              hipStream_t stream) {
  const float* x = (const float*)d_in[0];
  const int* src = (const int*)d_in[1];
  const int* dst = (const int*)d_in[2];
  const int* batch = (const int*)d_in[3];
  const float* W1_0 = (const float*)d_in[4];
  const float* b1_0 = (const float*)d_in[5];
  const float* W2_0 = (const float*)d_in[6];
  const float* b2_0 = (const float*)d_in[7];
  const float* W1_r = (const float*)d_in[8];
  const float* b1_r = (const float*)d_in[9];
  const float* W2_r = (const float*)d_in[10];
  const float* b2_r = (const float*)d_in[11];
  const float* bn_gamma = (const float*)d_in[12];
  const float* bn_beta = (const float*)d_in[13];
  const float* bn_mean = (const float*)d_in[14];
  const float* bn_var = (const float*)d_in[15];
  const float* Wc = (const float*)d_in[16];
  const float* bc = (const float*)d_in[17];
  float* out = (float*)d_out;

  char* base = (char*)d_ws;
  size_t off = 0;
  auto take = [&](size_t bytes) {
    size_t cur = off;
    off += (bytes + 255) & ~(size_t)255;
    return cur;
  };
  int* bcur = (int*)(base + take((size_t)NBUK * 4));
  u64* pairs = (u64*)(base + take((size_t)NBUK * BCAP * 8));
  int* ncnt = (int*)(base + take((size_t)NN * 4));
  int* rowptr = (int*)(base + take((size_t)(NN + 1) * 4));
  int* esrc = (int*)(base + take((size_t)NE * 4));
  unsigned short* xb = (unsigned short*)(base + take((size_t)NN * 128 * 2));
  signed char* hq = (signed char*)(base + take((size_t)NN * 256));
  float* hscale = (float*)(base + take((size_t)NN * 4));
  signed char* hinq = (signed char*)(base + take((size_t)NN * 256));
  float* hinscale = (float*)(base + take((size_t)NN * 4));
  unsigned short* hin = (unsigned short*)(base + take((size_t)NN * 256 * 2));
  unsigned short* W1_0t = (unsigned short*)(base + take(256 * 128 * 2));
  unsigned short* W2_0t = (unsigned short*)(base + take(256 * 256 * 2));
  unsigned short* W1_rt = (unsigned short*)(base + take(3 * 256 * 256 * 2));
  unsigned short* W2_rt = (unsigned short*)(base + take(3 * 256 * 256 * 2));
  float* bnscale = (float*)(base + take(4 * 256 * 4));
  float* bnshift = (float*)(base + take(4 * 256 * 4));
  int* bsums = (int*)(base + take(NB_SCAN * 4));
  int* boff = (int*)(base + take(NB_SCAN * 4));
  (void)ws_size; (void)in_sizes; (void)n_in; (void)out_size;

  // bucketed CSR build
  (void)hipMemsetAsync(bcur, 0, (size_t)NBUK * 4, stream);
  p1_kernel<<<NP1, 256, 0, stream>>>(src, dst, bcur, pairs);
  bcount_kernel<<<NBUK, 256, 0, stream>>>(pairs, bcur, ncnt);
  bsum_kernel<<<NB_SCAN, 256, 0, stream>>>(ncnt, bsums);
  bscan_kernel<<<1, 128, 0, stream>>>(bsums, boff, rowptr);
  scan_apply_kernel<<<NB_SCAN, 256, 0, stream>>>(ncnt, boff, rowptr);
  p2_kernel<<<NBUK, 256, 0, stream>>>(pairs, bcur, rowptr, esrc);

  // conversions
  convx_kernel<<<NN * 128 / 4 / 256, 256, 0, stream>>>(x, xb);
  wconv_kernel<<<128, 256, 0, stream>>>(W1_0, W1_0t, 128, 256);
  wconv_kernel<<<256, 256, 0, stream>>>(W2_0, W2_0t, 256, 256);
  for (int i = 0; i < 3; ++i) {
    wconv_kernel<<<256, 256, 0, stream>>>(W1_r + (size_t)i * 65536, W1_rt + (size_t)i * 65536, 256, 256);
    wconv_kernel<<<256, 256, 0, stream>>>(W2_r + (size_t)i * 65536, W2_rt + (size_t)i * 65536, 256, 256);
  }
  bnprep_kernel<<<4, 256, 0, stream>>>(bn_gamma, bn_beta, bn_mean, bn_var, bnscale, bnshift);

  const int aggGrid = (NN + 3) / 4;
  const int mlpGrid = (NN + 63) / 64;

  // layer 0: agg128 (bf16) -> mlp128 -> hq/hscale
  agg128_kernel<<<aggGrid, 256, 0, stream>>>(xb, rowptr, esrc, hin);
  mlp_kernel<128><<<mlpGrid, 256, 0, stream>>>(hin, nullptr, nullptr, W1_0t, b1_0,
                                               W2_0t, b2_0, bnscale, bnshift,
                                               hq, hscale, NN);
  // layers 1..3: agg256 (int8 -> int8) -> mlp256 (int8 in) -> hq/hscale
  for (int i = 0; i < 3; ++i) {
    agg256_kernel<<<aggGrid, 256, 0, stream>>>(hq, hscale, rowptr, esrc, hinq, hinscale);
    mlp_kernel<256><<<mlpGrid, 256, 0, stream>>>(
        nullptr, hinq, hinscale, W1_rt + (size_t)i * 65536, b1_r + (size_t)i * 256,
        W2_rt + (size_t)i * 65536, b2_r + (size_t)i * 256,
        bnscale + (size_t)(i + 1) * 256, bnshift + (size_t)(i + 1) * 256, hq, hscale, NN);
  }

  pool_classify_kernel<<<NG, 256, 0, stream>>>(hq, hscale, batch, Wc, bc, out);
}

// Round 18
// 633.462 us; speedup vs baseline: 1.4842x; 1.0796x over previous
//
#include <hip/hip_runtime.h>
#include <stdint.h>

#define NN 100000
#define NE 1600000
#define NG 512
#define NB_SCAN ((NN + 1023) / 1024)
#define BSH 8                          // 256 nodes per bucket
#define NBUK ((NN + 255) >> 8)         // 391 buckets
#define BCAP 5120                      // slab capacity per bucket
#define P1CH 4096                      // edges per phase-1 block
#define NP1 ((NE + P1CH - 1) / P1CH)   // 391

typedef __attribute__((ext_vector_type(2))) float f32x2;
typedef __attribute__((ext_vector_type(2))) unsigned short u16x2;
typedef __attribute__((ext_vector_type(4))) unsigned short u16x4;
typedef __attribute__((ext_vector_type(4))) unsigned int u32x4;
typedef __attribute__((ext_vector_type(4))) int i32x4;
typedef __attribute__((ext_vector_type(8))) short bf16x8;
typedef __attribute__((ext_vector_type(4))) float f32x4;
typedef unsigned long long u64;

__device__ __forceinline__ float bf2f(unsigned short u) {
  union { unsigned int i; float f; } v; v.i = ((unsigned int)u) << 16; return v.f;
}
__device__ __forceinline__ unsigned short f2bf(float f) {
  union { float f; unsigned int i; } v; v.f = f;
  unsigned int x = v.i;
  return (unsigned short)((x + 0x7fffu + ((x >> 16) & 1u)) >> 16);
}

// ================= bucketed CSR build =================
__global__ __launch_bounds__(256) void p1_kernel(const int* __restrict__ src,
                                                 const int* __restrict__ dst,
                                                 int* __restrict__ bcur,
                                                 u64* __restrict__ pairs) {
  __shared__ u64 buf[P1CH];
  __shared__ int cnt[NBUK], off[NBUK], place[NBUK], gbase[NBUK];
  int tid = threadIdx.x;
  int e0 = blockIdx.x * P1CH;
  int ecnt = min(P1CH, NE - e0);
  for (int i = tid; i < NBUK; i += 256) cnt[i] = 0;
  __syncthreads();
  int ls[16], ld[16];
#pragma unroll
  for (int k = 0; k < 16; ++k) {
    int i = tid + k * 256;
    if (i < ecnt) {
      ls[k] = src[e0 + i];
      ld[k] = dst[e0 + i];
      atomicAdd(&cnt[ld[k] >> BSH], 1);
    }
  }
  __syncthreads();
  if (tid < 64) {
    int base = tid * 7;
    int loc[7];
    int s = 0;
#pragma unroll
    for (int k = 0; k < 7; ++k) {
      int idx = base + k;
      int v = (idx < NBUK) ? cnt[idx] : 0;
      loc[k] = s; s += v;
    }
    int incl = s;
    for (int o = 1; o < 64; o <<= 1) {
      int t = __shfl_up(incl, o, 64);
      if (tid >= o) incl += t;
    }
    int ex = incl - s;
#pragma unroll
    for (int k = 0; k < 7; ++k) {
      int idx = base + k;
      if (idx < NBUK) { off[idx] = ex + loc[k]; place[idx] = ex + loc[k]; }
    }
  }
  __syncthreads();
  for (int b = tid; b < NBUK; b += 256)
    if (cnt[b] > 0) gbase[b] = atomicAdd(&bcur[b], cnt[b]);
  __syncthreads();
#pragma unroll
  for (int k = 0; k < 16; ++k) {
    int i = tid + k * 256;
    if (i < ecnt) {
      int b = ld[k] >> BSH;
      int p = atomicAdd(&place[b], 1);
      buf[p] = ((u64)(unsigned)ld[k] << 32) | (unsigned)ls[k];
    }
  }
  __syncthreads();
  for (int i = tid; i < ecnt; i += 256) {
    u64 pr = buf[i];
    int b = (int)(pr >> 32) >> BSH;
    int idx = gbase[b] + (i - off[b]);
    pairs[(size_t)b * BCAP + idx] = pr;
  }
}

__global__ __launch_bounds__(256) void bcount_kernel(const u64* __restrict__ pairs,
                                                     const int* __restrict__ bcur,
                                                     int* __restrict__ ncnt) {
  int b = blockIdx.x, tid = threadIdx.x;
  __shared__ int cnt[256];
  cnt[tid] = 0;
  __syncthreads();
  int n = bcur[b];
  const u64* pp = pairs + (size_t)b * BCAP;
  for (int i = tid; i < n; i += 256) {
    int d = (int)(pp[i] >> 32);
    atomicAdd(&cnt[d & 255], 1);
  }
  __syncthreads();
  int node = (b << BSH) + tid;
  if (node < NN) ncnt[node] = cnt[tid];
}

__global__ __launch_bounds__(256) void p2_kernel(const u64* __restrict__ pairs,
                                                 const int* __restrict__ bcur,
                                                 const int* __restrict__ rowptr,
                                                 int* __restrict__ esrc) {
  int b = blockIdx.x, tid = threadIdx.x;
  __shared__ int cur[256];
  int node = (b << BSH) + tid;
  cur[tid] = (node < NN) ? rowptr[node] : 0;
  __syncthreads();
  int n = bcur[b];
  const u64* pp = pairs + (size_t)b * BCAP;
  for (int i = tid; i < n; i += 256) {
    u64 pr = pp[i];
    int s = (int)(pr & 0xffffffffu);
    int d = (int)(pr >> 32);
    int p = atomicAdd(&cur[d & 255], 1);
    esrc[p] = s;
  }
}

__global__ __launch_bounds__(256) void bsum_kernel(const int* __restrict__ counts,
                                                   int* __restrict__ bsums) {
  __shared__ int red[256];
  int b = blockIdx.x, tid = threadIdx.x;
  int s = 0;
#pragma unroll
  for (int k = 0; k < 4; ++k) {
    int i = b * 1024 + k * 256 + tid;
    if (i < NN) s += counts[i];
  }
  red[tid] = s;
  __syncthreads();
  for (int off = 128; off > 0; off >>= 1) {
    if (tid < off) red[tid] += red[tid + off];
    __syncthreads();
  }
  if (tid == 0) bsums[b] = red[0];
}

__global__ __launch_bounds__(128) void bscan_kernel(const int* __restrict__ bsums,
                                                    int* __restrict__ boff,
                                                    int* __restrict__ rowptr) {
  __shared__ int buf[128];
  int tid = threadIdx.x;
  int v = (tid < NB_SCAN) ? bsums[tid] : 0;
  buf[tid] = v;
  __syncthreads();
  int incl = v;
  for (int off = 1; off < 128; off <<= 1) {
    int add = (tid >= off) ? buf[tid - off] : 0;
    __syncthreads();
    incl += add;
    buf[tid] = incl;
    __syncthreads();
  }
  if (tid < NB_SCAN) boff[tid] = incl - v;
  if (tid == NB_SCAN - 1) rowptr[NN] = incl;
}

__global__ __launch_bounds__(256) void scan_apply_kernel(const int* __restrict__ counts,
                                                         const int* __restrict__ boff,
                                                         int* __restrict__ rowptr) {
  __shared__ int tsum[256];
  int b = blockIdx.x, tid = threadIdx.x;
  int base = b * 1024 + tid * 4;
  int c[4];
  if (base + 3 < NN) {
    i32x4 cv = *(const i32x4*)(counts + base);
    c[0] = cv[0]; c[1] = cv[1]; c[2] = cv[2]; c[3] = cv[3];
  } else {
#pragma unroll
    for (int k = 0; k < 4; ++k) c[k] = (base + k < NN) ? counts[base + k] : 0;
  }
  int s = c[0] + c[1] + c[2] + c[3];
  tsum[tid] = s;
  __syncthreads();
  int incl = s;
  for (int off = 1; off < 256; off <<= 1) {
    int add = (tid >= off) ? tsum[tid - off] : 0;
    __syncthreads();
    incl += add;
    tsum[tid] = incl;
    __syncthreads();
  }
  int ex = boff[b] + incl - s;
#pragma unroll
  for (int k = 0; k < 4; ++k) {
    int i = base + k;
    if (i < NN) rowptr[i] = ex;
    ex += c[k];
  }
}

// ---------------- conversions ----------------
__global__ __launch_bounds__(256) void convx_kernel(const float* __restrict__ x,
                                                    unsigned short* __restrict__ xb) {
  int t = blockIdx.x * 256 + threadIdx.x;
  int i = t * 4;
  if (i < NN * 128) {
    f32x4 v = *(const f32x4*)(x + i);
    u16x4 o;
    o[0] = f2bf(v[0]); o[1] = f2bf(v[1]); o[2] = f2bf(v[2]); o[3] = f2bf(v[3]);
    *(u16x4*)(xb + i) = o;
  }
}

__global__ __launch_bounds__(256) void wconv_kernel(const float* __restrict__ W,
                                                    unsigned short* __restrict__ Wt,
                                                    int K, int ncols) {
  int t = blockIdx.x * 256 + threadIdx.x;
  if (t < K * ncols) {
    int k = t / ncols, n = t % ncols;
    Wt[n * K + k] = f2bf(W[t]);
  }
}

__global__ __launch_bounds__(256) void bnprep_kernel(const float* __restrict__ gamma,
                                                     const float* __restrict__ beta,
                                                     const float* __restrict__ mean,
                                                     const float* __restrict__ var,
                                                     float* __restrict__ scale,
                                                     float* __restrict__ shift) {
  int t = blockIdx.x * 256 + threadIdx.x;
  if (t < 4 * 256) {
    float s = gamma[t] * rsqrtf(var[t] + 1e-5f);
    scale[t] = s;
    shift[t] = beta[t] - mean[t] * s;
  }
}

// ---------------- aggregation ----------------
__device__ __forceinline__ void deq4(int w, float s, float& a0, float& a1, float& a2, float& a3) {
  a0 += s * (float)((w << 24) >> 24);
  a1 += s * (float)((w << 16) >> 24);
  a2 += s * (float)((w << 8) >> 24);
  a3 += s * (float)(w >> 24);
}

// agg256: int8 table in, int8 (+scale) out — wave-shuffle absmax, no barriers
__global__ __launch_bounds__(256, 8) void agg256_kernel(const signed char* __restrict__ hq,
                                                        const float* __restrict__ hs,
                                                        const int* __restrict__ rowptr,
                                                        const int* __restrict__ esrc,
                                                        signed char* __restrict__ outq,
                                                        float* __restrict__ outs) {
  int node = blockIdx.x * 4 + (threadIdx.x >> 6);
  int lane = threadIdx.x & 63;
  if (node >= NN) return;
  const int* __restrict__ hv = (const int*)hq;  // 4 int8 per lane
  float a0 = 0.f, a1 = 0.f, a2 = 0.f, a3 = 0.f;
  deq4(hv[(size_t)node * 64 + lane], hs[node], a0, a1, a2, a3);
  int p = rowptr[node];
  const int pe = rowptr[node + 1];
  for (; p + 16 <= pe; p += 16) {
    int idx[16];
#pragma unroll
    for (int j = 0; j < 16; ++j) idx[j] = esrc[p + j];
    int w[16]; float sc[16];
#pragma unroll
    for (int j = 0; j < 16; ++j) { w[j] = hv[(size_t)idx[j] * 64 + lane]; sc[j] = hs[idx[j]]; }
#pragma unroll
    for (int j = 0; j < 16; ++j) deq4(w[j], sc[j], a0, a1, a2, a3);
  }
  for (; p + 4 <= pe; p += 4) {
    int idx[4];
#pragma unroll
    for (int j = 0; j < 4; ++j) idx[j] = esrc[p + j];
    int w[4]; float sc[4];
#pragma unroll
    for (int j = 0; j < 4; ++j) { w[j] = hv[(size_t)idx[j] * 64 + lane]; sc[j] = hs[idx[j]]; }
#pragma unroll
    for (int j = 0; j < 4; ++j) deq4(w[j], sc[j], a0, a1, a2, a3);
  }
  for (; p < pe; ++p) deq4(hv[(size_t)esrc[p] * 64 + lane], hs[esrc[p]], a0, a1, a2, a3);
  // per-node absmax via wave butterfly, then int8 quant (1 dword/lane, coalesced)
  float m = fmaxf(fmaxf(fabsf(a0), fabsf(a1)), fmaxf(fabsf(a2), fabsf(a3)));
  for (int o = 1; o < 64; o <<= 1) m = fmaxf(m, __shfl_xor(m, o, 64));
  m = fmaxf(m, 1e-20f);
  float inv = 127.f / m;
  int q0 = __float2int_rn(a0 * inv), q1 = __float2int_rn(a1 * inv);
  int q2 = __float2int_rn(a2 * inv), q3 = __float2int_rn(a3 * inv);
  unsigned int pk = (q0 & 255) | ((q1 & 255) << 8) | ((q2 & 255) << 16) | ((q3 & 255) << 24);
  ((unsigned int*)outq)[(size_t)node * 64 + lane] = pk;
  if (lane == 0) outs[node] = m * (1.f / 127.f);
}

// agg128: bf16 x-table, bf16 out (layer 0)
__global__ __launch_bounds__(256, 8) void agg128_kernel(const unsigned short* __restrict__ h,
                                                        const int* __restrict__ rowptr,
                                                        const int* __restrict__ esrc,
                                                        unsigned short* __restrict__ out) {
  int node = blockIdx.x * 4 + (threadIdx.x >> 6);
  int lane = threadIdx.x & 63;
  if (node >= NN) return;
  const u16x2* __restrict__ hv = (const u16x2*)h;
  u16x2 v = hv[(size_t)node * 64 + lane];
  float a0 = bf2f(v[0]), a1 = bf2f(v[1]);
  int p = rowptr[node];
  const int pe = rowptr[node + 1];
  for (; p + 8 <= pe; p += 8) {
    int idx[8];
#pragma unroll
    for (int j = 0; j < 8; ++j) idx[j] = esrc[p + j];
    u16x2 u[8];
#pragma unroll
    for (int j = 0; j < 8; ++j) u[j] = hv[(size_t)idx[j] * 64 + lane];
#pragma unroll
    for (int j = 0; j < 8; ++j) { a0 += bf2f(u[j][0]); a1 += bf2f(u[j][1]); }
  }
  for (; p < pe; ++p) {
    u16x2 u = hv[(size_t)esrc[p] * 64 + lane];
    a0 += bf2f(u[0]); a1 += bf2f(u[1]);
  }
  u16x2 o; o[0] = f2bf(a0); o[1] = f2bf(a1);
  ((u16x2*)out)[(size_t)node * 64 + lane] = o;
}

// ---- fused 2-layer MLP + BN + ReLU -> int8 out (LDS-packed coalesced stores) ----
template <int K>
__global__ __launch_bounds__(256, 4) void mlp_kernel(
    const unsigned short* __restrict__ hinb, const signed char* __restrict__ hinq,
    const float* __restrict__ hins, const unsigned short* __restrict__ W1t,
    const float* __restrict__ b1, const unsigned short* __restrict__ W2t,
    const float* __restrict__ b2, const float* __restrict__ bnscale,
    const float* __restrict__ bnshift, signed char* __restrict__ hq,
    float* __restrict__ hscale, int M) {
  constexpr int AP = K + 8;
  constexpr int SP = 264;
  __shared__ unsigned short buf[64 * 264];   // 33792 B, reused A -> S -> int8 pack
  __shared__ float wmax[4][64];
  __shared__ float rowinv[64];
  int tid = threadIdx.x;
  int lane = tid & 63, w = tid >> 6;
  int l16 = lane & 15, lhi = lane >> 4;
  int row0 = blockIdx.x * 64;

  // stage A tile (64 x K)
  if constexpr (K == 128) {
    constexpr int CH = 64 * K / 8;
    for (int ch = tid; ch < CH; ch += 256) {
      int r = ch / (K / 8);
      int c = (ch % (K / 8)) * 8;
      u32x4 val = {0u, 0u, 0u, 0u};
      if (row0 + r < M) val = *(const u32x4*)(hinb + (size_t)(row0 + r) * K + c);
      *(u32x4*)(&buf[r * AP + c]) = val;
    }
  } else {
    for (int ch = tid; ch < 2048; ch += 256) {
      int r = ch >> 5;
      int c = (ch & 31) * 8;
      int gr = row0 + r;
      unsigned int w0 = 0u, w1 = 0u; float s = 0.f;
      if (gr < M) {
        const unsigned int* p = (const unsigned int*)(hinq + (size_t)gr * 256 + c);
        w0 = p[0]; w1 = p[1];
        s = hins[gr];
      }
      u32x4 outv;
#pragma unroll
      for (int h = 0; h < 2; ++h) {
        unsigned int wv = h ? w1 : w0;
        unsigned short c0 = f2bf(s * (float)((int)(wv << 24) >> 24));
        unsigned short c1 = f2bf(s * (float)((int)(wv << 16) >> 24));
        unsigned short c2 = f2bf(s * (float)((int)(wv << 8) >> 24));
        unsigned short c3 = f2bf(s * (float)((int)wv >> 24));
        outv[2 * h] = (unsigned)c0 | ((unsigned)c1 << 16);
        outv[2 * h + 1] = (unsigned)c2 | ((unsigned)c3 << 16);
      }
      *(u32x4*)(&buf[r * AP + c]) = outv;
    }
  }
  __syncthreads();

  // phase A: acc = A @ W1
  f32x4 acc[4][4] = {};
#pragma unroll
  for (int ks = 0; ks < K / 32; ++ks) {
    int kk = ks * 32 + lhi * 8;
    bf16x8 a[4], b[4];
#pragma unroll
    for (int mf = 0; mf < 4; ++mf)
      a[mf] = *(const bf16x8*)(&buf[(16 * mf + l16) * AP + kk]);
#pragma unroll
    for (int nf = 0; nf < 4; ++nf)
      b[nf] = *(const bf16x8*)(W1t + (size_t)(64 * w + 16 * nf + l16) * K + kk);
#pragma unroll
    for (int mf = 0; mf < 4; ++mf)
#pragma unroll
      for (int nf = 0; nf < 4; ++nf)
        acc[mf][nf] = __builtin_amdgcn_mfma_f32_16x16x32_bf16(a[mf], b[nf], acc[mf][nf], 0, 0, 0);
  }
  __syncthreads();

  // S = relu(acc + b1) into buf
#pragma unroll
  for (int nf = 0; nf < 4; ++nf) {
    int col = 64 * w + 16 * nf + l16;
    float bias = b1[col];
#pragma unroll
    for (int mf = 0; mf < 4; ++mf) {
      f32x4 v = acc[mf][nf];
#pragma unroll
      for (int j = 0; j < 4; ++j) {
        float x = v[j] + bias;
        x = fmaxf(x, 0.f);
        buf[(16 * mf + lhi * 4 + j) * SP + col] = f2bf(x);
      }
    }
  }
  __syncthreads();

  // phase B: acc2 = S @ W2
  f32x4 acc2[4][4] = {};
#pragma unroll
  for (int ks = 0; ks < 8; ++ks) {
    int kk = ks * 32 + lhi * 8;
    bf16x8 a[4], b[4];
#pragma unroll
    for (int mf = 0; mf < 4; ++mf)
      a[mf] = *(const bf16x8*)(&buf[(16 * mf + l16) * SP + kk]);
#pragma unroll
    for (int nf = 0; nf < 4; ++nf)
      b[nf] = *(const bf16x8*)(W2t + (size_t)(64 * w + 16 * nf + l16) * 256 + kk);
#pragma unroll
    for (int mf = 0; mf < 4; ++mf)
#pragma unroll
      for (int nf = 0; nf < 4; ++nf)
        acc2[mf][nf] = __builtin_amdgcn_mfma_f32_16x16x32_bf16(a[mf], b[nf], acc2[mf][nf], 0, 0, 0);
  }

  // epilogue: BN+ReLU in regs; per-row max via shuffles
  float pmax[4][4];
#pragma unroll
  for (int mf = 0; mf < 4; ++mf)
#pragma unroll
    for (int j = 0; j < 4; ++j) pmax[mf][j] = 0.f;
#pragma unroll
  for (int nf = 0; nf < 4; ++nf) {
    int col = 64 * w + 16 * nf + l16;
    float bias = b2[col], sc = bnscale[col], sh = bnshift[col];
#pragma unroll
    for (int mf = 0; mf < 4; ++mf) {
#pragma unroll
      for (int j = 0; j < 4; ++j) {
        float x = acc2[mf][nf][j] + bias;
        x = x * sc + sh;
        x = fmaxf(x, 0.f);
        acc2[mf][nf][j] = x;
        pmax[mf][j] = fmaxf(pmax[mf][j], x);
      }
    }
  }
#pragma unroll
  for (int mf = 0; mf < 4; ++mf) {
#pragma unroll
    for (int j = 0; j < 4; ++j) {
      float m = pmax[mf][j];
      m = fmaxf(m, __shfl_xor(m, 1, 16));
      m = fmaxf(m, __shfl_xor(m, 2, 16));
      m = fmaxf(m, __shfl_xor(m, 4, 16));
      m = fmaxf(m, __shfl_xor(m, 8, 16));
      pmax[mf][j] = m;
    }
  }
  if (l16 == 0) {
#pragma unroll
    for (int mf = 0; mf < 4; ++mf)
#pragma unroll
      for (int j = 0; j < 4; ++j)
        wmax[w][16 * mf + lhi * 4 + j] = pmax[mf][j];
  }
  __syncthreads();
  if (tid < 64) {
    float m = fmaxf(fmaxf(wmax[0][tid], wmax[1][tid]), fmaxf(wmax[2][tid], wmax[3][tid]));
    m = fmaxf(m, 1e-20f);
    rowinv[tid] = 127.f / m;
    int r = row0 + tid;
    if (r < M) hscale[r] = m * (1.f / 127.f);
  }
  __syncthreads();

  // quantize into LDS bytes, then coalesced 16B copy-out
  char* bufc = (char*)buf;
#pragma unroll
  for (int mf = 0; mf < 4; ++mf) {
#pragma unroll
    for (int j = 0; j < 4; ++j) {
      int lr = 16 * mf + lhi * 4 + j;
      float inv = rowinv[lr];
#pragma unroll
      for (int nf = 0; nf < 4; ++nf) {
        int col = 64 * w + 16 * nf + l16;
        int q = __float2int_rn(acc2[mf][nf][j] * inv);
        bufc[lr * 256 + col] = (char)q;
      }
    }
  }
  __syncthreads();
  for (int ch = tid; ch < 64 * 16; ch += 256) {   // 1024 chunks of 16B
    int r = ch >> 4;
    int c = (ch & 15) * 16;
    if (row0 + r < M)
      *(u32x4*)(hq + (size_t)(row0 + r) * 256 + c) = *(const u32x4*)(bufc + r * 256 + c);
  }
}

// ---------------- pooling + classifier (row-parallel across 4 waves) ----------------
__global__ __launch_bounds__(256) void pool_classify_kernel(
    const signed char* __restrict__ hq, const float* __restrict__ hs,
    const int* __restrict__ batch, const float* __restrict__ Wc,
    const float* __restrict__ bc, float* __restrict__ out) {
  int g = blockIdx.x;
  int tid = threadIdx.x;
  int w = tid >> 6, lane = tid & 63;
  __shared__ int bounds[2];
  if (tid < 2) {
    int target = g + tid;
    int lo = 0, hi = NN;
    while (lo < hi) {
      int mid = (lo + hi) >> 1;
      if (batch[mid] < target) lo = mid + 1; else hi = mid;
    }
    bounds[tid] = lo;
  }
  __syncthreads();
  int s = bounds[0], e = bounds[1];
  // wave w takes rows s+w, s+w+4, ...; lane covers cols [lane*4, lane*4+4)
  float a0 = 0.f, a1 = 0.f, a2 = 0.f, a3 = 0.f;
  int i = s + w;
  for (; i + 4 < e; i += 8) {      // 2-deep unroll for MLP
    float sA = hs[i], sB = hs[i + 4];
    unsigned int wA = *(const unsigned int*)(hq + (size_t)i * 256 + lane * 4);
    unsigned int wB = *(const unsigned int*)(hq + (size_t)(i + 4) * 256 + lane * 4);
    a0 += sA * (float)((int)(wA << 24) >> 24) + sB * (float)((int)(wB << 24) >> 24);
    a1 += sA * (float)((int)(wA << 16) >> 24) + sB * (float)((int)(wB << 16) >> 24);
    a2 += sA * (float)((int)(wA << 8) >> 24) + sB * (float)((int)(wB << 8) >> 24);
    a3 += sA * (float)((int)wA >> 24) + sB * (float)((int)wB >> 24);
  }
  for (; i < e; i += 4) {
    float sA = hs[i];
    unsigned int wA = *(const unsigned int*)(hq + (size_t)i * 256 + lane * 4);
    a0 += sA * (float)((int)(wA << 24) >> 24);
    a1 += sA * (float)((int)(wA << 16) >> 24);
    a2 += sA * (float)((int)(wA << 8) >> 24);
    a3 += sA * (float)((int)wA >> 24);
  }
  __shared__ float ps[4][256];
  ps[w][lane * 4 + 0] = a0;
  ps[w][lane * 4 + 1] = a1;
  ps[w][lane * 4 + 2] = a2;
  ps[w][lane * 4 + 3] = a3;
  __syncthreads();
  float colsum = ps[0][tid] + ps[1][tid] + ps[2][tid] + ps[3][tid];
  int cnt = e - s;
  float p = colsum / (float)(cnt > 1 ? cnt : 1);
  __shared__ float red[256];
  for (int c = 0; c < 10; ++c) {
    red[tid] = p * Wc[tid * 10 + c];
    __syncthreads();
    for (int off = 128; off > 0; off >>= 1) {
      if (tid < off) red[tid] += red[tid + off];
      __syncthreads();
    }
    if (tid == 0) out[g * 10 + c] = red[0] + bc[c];
    __syncthreads();
  }
}

extern "C" void kernel_launch(void* const* d_in, const int* in_sizes, int n_in,
                              void* d_out, int out_size, void* d_ws, size_t ws_size,
                              hipStream_t stream) {
  const float* x = (const float*)d_in[0];
  const int* src = (const int*)d_in[1];
  const int* dst = (const int*)d_in[2];
  const int* batch = (const int*)d_in[3];
  const float* W1_0 = (const float*)d_in[4];
  const float* b1_0 = (const float*)d_in[5];
  const float* W2_0 = (const float*)d_in[6];
  const float* b2_0 = (const float*)d_in[7];
  const float* W1_r = (const float*)d_in[8];
  const float* b1_r = (const float*)d_in[9];
  const float* W2_r = (const float*)d_in[10];
  const float* b2_r = (const float*)d_in[11];
  const float* bn_gamma = (const float*)d_in[12];
  const float* bn_beta = (const float*)d_in[13];
  const float* bn_mean = (const float*)d_in[14];
  const float* bn_var = (const float*)d_in[15];
  const float* Wc = (const float*)d_in[16];
  const float* bc = (const float*)d_in[17];
  float* out = (float*)d_out;

  char* base = (char*)d_ws;
  size_t off = 0;
  auto take = [&](size_t bytes) {
    size_t cur = off;
    off += (bytes + 255) & ~(size_t)255;
    return cur;
  };
  int* bcur = (int*)(base + take((size_t)NBUK * 4));
  u64* pairs = (u64*)(base + take((size_t)NBUK * BCAP * 8));
  int* ncnt = (int*)(base + take((size_t)NN * 4));
  int* rowptr = (int*)(base + take((size_t)(NN + 1) * 4));
  int* esrc = (int*)(base + take((size_t)NE * 4));
  unsigned short* xb = (unsigned short*)(base + take((size_t)NN * 128 * 2));
  signed char* hq = (signed char*)(base + take((size_t)NN * 256));
  float* hscale = (float*)(base + take((size_t)NN * 4));
  signed char* hinq = (signed char*)(base + take((size_t)NN * 256));
  float* hinscale = (float*)(base + take((size_t)NN * 4));
  unsigned short* hin = (unsigned short*)(base + take((size_t)NN * 256 * 2));
  unsigned short* W1_0t = (unsigned short*)(base + take(256 * 128 * 2));
  unsigned short* W2_0t = (unsigned short*)(base + take(256 * 256 * 2));
  unsigned short* W1_rt = (unsigned short*)(base + take(3 * 256 * 256 * 2));
  unsigned short* W2_rt = (unsigned short*)(base + take(3 * 256 * 256 * 2));
  float* bnscale = (float*)(base + take(4 * 256 * 4));
  float* bnshift = (float*)(base + take(4 * 256 * 4));
  int* bsums = (int*)(base + take(NB_SCAN * 4));
  int* boff = (int*)(base + take(NB_SCAN * 4));
  (void)ws_size; (void)in_sizes; (void)n_in; (void)out_size;

  // bucketed CSR build
  (void)hipMemsetAsync(bcur, 0, (size_t)NBUK * 4, stream);
  p1_kernel<<<NP1, 256, 0, stream>>>(src, dst, bcur, pairs);
  bcount_kernel<<<NBUK, 256, 0, stream>>>(pairs, bcur, ncnt);
  bsum_kernel<<<NB_SCAN, 256, 0, stream>>>(ncnt, bsums);
  bscan_kernel<<<1, 128, 0, stream>>>(bsums, boff, rowptr);
  scan_apply_kernel<<<NB_SCAN, 256, 0, stream>>>(ncnt, boff, rowptr);
  p2_kernel<<<NBUK, 256, 0, stream>>>(pairs, bcur, rowptr, esrc);

  // conversions
  convx_kernel<<<NN * 128 / 4 / 256, 256, 0, stream>>>(x, xb);
  wconv_kernel<<<128, 256, 0, stream>>>(W1_0, W1_0t, 128, 256);
  wconv_kernel<<<256, 256, 0, stream>>>(W2_0, W2_0t, 256, 256);
  for (int i = 0; i < 3; ++i) {
    wconv_kernel<<<256, 256, 0, stream>>>(W1_r + (size_t)i * 65536, W1_rt + (size_t)i * 65536, 256, 256);
    wconv_kernel<<<256, 256, 0, stream>>>(W2_r + (size_t)i * 65536, W2_rt + (size_t)i * 65536, 256, 256);
  }
  bnprep_kernel<<<4, 256, 0, stream>>>(bn_gamma, bn_beta, bn_mean, bn_var, bnscale, bnshift);

  const int aggGrid = (NN + 3) / 4;
  const int mlpGrid = (NN + 63) / 64;

  // layer 0: agg128 (bf16) -> mlp128 -> hq/hscale
  agg128_kernel<<<aggGrid, 256, 0, stream>>>(xb, rowptr, esrc, hin);
  mlp_kernel<128><<<mlpGrid, 256, 0, stream>>>(hin, nullptr, nullptr, W1_0t, b1_0,
                                               W2_0t, b2_0, bnscale, bnshift,
                                               hq, hscale, NN);
  // layers 1..3: agg256 (int8 -> int8) -> mlp256 (int8 in) -> hq/hscale
  for (int i = 0; i < 3; ++i) {
    agg256_kernel<<<aggGrid, 256, 0, stream>>>(hq, hscale, rowptr, esrc, hinq, hinscale);
    mlp_kernel<256><<<mlpGrid, 256, 0, stream>>>(
        nullptr, hinq, hinscale, W1_rt + (size_t)i * 65536, b1_r + (size_t)i * 256,
        W2_rt + (size_t)i * 65536, b2_r + (size_t)i * 256,
        bnscale + (size_t)(i + 1) * 256, bnshift + (size_t)(i + 1) * 256, hq, hscale, NN);
  }

  pool_classify_kernel<<<NG, 256, 0, stream>>>(hq, hscale, batch, Wc, bc, out);
}